// Round 7
// baseline (5984.663 us; speedup 1.0000x reference)
//
#include <hip/hip_runtime.h>
#include <math.h>

// Problem dims (fixed by reference)
#define BB 32
#define CC 8
#define TT 64
#define FF 256
#define HH 512
#define G3 1536
#define NSEQ 256            // BB*CC
#define MROWS 16384         // NSEQ*TT

typedef _Float16 f16x8 __attribute__((ext_vector_type(8)));
typedef float f32x4 __attribute__((ext_vector_type(4)));

// ---------------- input GEMM: C[M][N] = A[M][K] @ W[N][K]^T + bias[N] ----------------
#define TMg 128
#define TNg 128
#define TKg 16

__global__ __launch_bounds__(256) void gemm_bias(
    const float* __restrict__ A, const float* __restrict__ W,
    const float* __restrict__ bias, float* __restrict__ C,
    int M, int N, int K)
{
  __shared__ float As[TKg][TMg + 4];
  __shared__ float Ws[TKg][TNg + 4];
  const int bm = blockIdx.y * TMg;
  const int bn = blockIdx.x * TNg;
  const int tid = threadIdx.x;
  const int tx = tid & 15;
  const int ty = tid >> 4;
  float acc[8][8];
#pragma unroll
  for (int i = 0; i < 8; ++i)
#pragma unroll
    for (int j = 0; j < 8; ++j) acc[i][j] = 0.f;

  for (int k0 = 0; k0 < K; k0 += TKg) {
    __syncthreads();
#pragma unroll
    for (int i = 0; i < 8; ++i) {
      int e = i * 256 + tid;
      int r = e >> 4;
      int c = e & 15;
      As[c][r] = A[(size_t)(bm + r) * K + (k0 + c)];
      Ws[c][r] = W[(size_t)(bn + r) * K + (k0 + c)];
    }
    __syncthreads();
#pragma unroll
    for (int k = 0; k < TKg; ++k) {
      float a[8], w[8];
#pragma unroll
      for (int i = 0; i < 8; ++i) a[i] = As[k][ty * 8 + i];
#pragma unroll
      for (int j = 0; j < 8; ++j) w[j] = Ws[k][tx + 16 * j];
#pragma unroll
      for (int i = 0; i < 8; ++i)
#pragma unroll
        for (int j = 0; j < 8; ++j) acc[i][j] = fmaf(a[i], w[j], acc[i][j]);
    }
  }
#pragma unroll
  for (int i = 0; i < 8; ++i) {
    size_t m = (size_t)(bm + ty * 8 + i);
#pragma unroll
    for (int j = 0; j < 8; ++j) {
      int n = bn + tx + 16 * j;
      C[m * N + n] = acc[i][j] + bias[n];
    }
  }
}

// ---------------- pack Whh[G3][HH] fp32 -> single fp16 plane, B-fragment order --------
// P[tile(96)][kc(16)][lane(64)][8 f16]
// B-frag (16x16x32_f16): n = lane&15 (Whh row within tile), k = kc*32 + (lane>>4)*8 + i
__global__ __launch_bounds__(256) void pack_whh(
    const float* __restrict__ W, _Float16* __restrict__ P)
{
  int id = blockIdx.x * 256 + threadIdx.x;    // 0 .. 98303
  int lane = id & 63;
  int kc = (id >> 6) & 15;
  int tile = id >> 10;                        // 0..95
  int row = tile * 16 + (lane & 15);
  int k0 = kc * 32 + ((lane >> 4) * 8);
  const float* src = W + (size_t)row * HH + k0;
  f16x8 hi;
#pragma unroll
  for (int i = 0; i < 8; ++i) hi[i] = (_Float16)src[i];
  *reinterpret_cast<f16x8*>(P + ((size_t)(tile * 16 + kc) * 64 + lane) * 8) = hi;
}

// ---------------- MFMA recurrent scan, LDS-staged weight stream ----------------
// 16 blocks x 16 seqs x 1024 threads (16 waves). Weights (1.5 MB fp16 pack,
// L2-resident) stream through a double-buffered 64 KB LDS chunk pipeline via
// async global_load_lds (no VGPR cost, deep in-flight window). 24 chunks of
// 4 tiles per step; chunk 23 stages chunk 0 for the NEXT step (weights repeat,
// so the pipeline never breaks). Owner waves (4 per chunk) compute their tile
// from LDS; gate epilogue is register-local per lane (validated absmax~0).
#define SPB2 16
#define HSTR 520
#define NCHUNK 24
#define CHUNK_F16 32768     // 4 tiles * 16 KB / 2 B

__device__ __forceinline__ void gload16(const _Float16* g, _Float16* l) {
  __builtin_amdgcn_global_load_lds(
      (const __attribute__((address_space(1))) unsigned int*)g,
      (__attribute__((address_space(3))) unsigned int*)l, 16, 0, 0);
}

// stage next chunk; compute this chunk if this wave owns a tile in it; barrier.
#define CH(c, accv)                                                              \
  {                                                                              \
    {                                                                            \
      const _Float16* gs = packW + (size_t)(((c) + 1) % NCHUNK) * CHUNK_F16      \
                           + wid * 2048 + lane * 8;                              \
      _Float16* ls = &wls[((c) + 1) & 1][wid * 2048];                            \
      gload16(gs, ls);                                                           \
      gload16(gs + 512, ls + 512);                                               \
      gload16(gs + 1024, ls + 1024);                                             \
      gload16(gs + 1536, ls + 1536);                                             \
    }                                                                            \
    if ((wid >> 2) == ((c) & 3)) {                                               \
      const _Float16* wt = &wls[(c) & 1][(wid & 3) * 8192];                      \
      f32x4 ae = {0.f, 0.f, 0.f, 0.f}, ao = {0.f, 0.f, 0.f, 0.f};                \
      _Pragma("unroll")                                                          \
      for (int kc = 0; kc < 16; kc += 2) {                                       \
        f16x8 ha0 = *reinterpret_cast<const f16x8*>(&hs[arow][kc * 32 + agrp * 8]); \
        f16x8 wb0 = *reinterpret_cast<const f16x8*>(wt + (size_t)kc * 512 + lane * 8); \
        ae = __builtin_amdgcn_mfma_f32_16x16x32_f16(ha0, wb0, ae, 0, 0, 0);      \
        f16x8 ha1 = *reinterpret_cast<const f16x8*>(&hs[arow][(kc + 1) * 32 + agrp * 8]); \
        f16x8 wb1 = *reinterpret_cast<const f16x8*>(wt + (size_t)(kc + 1) * 512 + lane * 8); \
        ao = __builtin_amdgcn_mfma_f32_16x16x32_f16(ha1, wb1, ao, 0, 0, 0);      \
      }                                                                          \
      accv = ae + ao;                                                            \
    }                                                                            \
    __syncthreads();                                                             \
  }

__global__ __launch_bounds__(1024, 4) void gru_scan_mfma(
    const float* __restrict__ gi,      // [NSEQ][TT][G3]
    const _Float16* __restrict__ packW,
    const float* __restrict__ bhh,     // [G3]
    float* __restrict__ hfin,          // [NSEQ][HH]
    float* __restrict__ yout)          // [NSEQ][TT][HH] or nullptr
{
  __shared__ __align__(16) _Float16 wls[2][CHUNK_F16];   // 128 KB weight dbuf
  __shared__ __align__(16) _Float16 hs[SPB2][HSTR];      // 16.6 KB h (single buf)

  const int tid = threadIdx.x;
  const int lane = tid & 63;
  const int wid = tid >> 6;                   // 0..15
  const int seq0 = blockIdx.x * SPB2;

  const int arow = lane & 15;                 // A-frag row (seq)
  const int agrp = lane >> 4;
  const int dcol = lane & 15;                 // D-frag col within tile
  const int mrow = (lane >> 4) * 4;           // D-frag first row (seq)

  const int cg0 = wid * 16 + dcol;            // column group w
  const int cg1 = cg0 + 256;                  // column group w+16

  // biases for this lane's two columns, all 3 gates
  const float bhr0 = bhh[cg0],        bhr1 = bhh[cg1];
  const float bhz0 = bhh[HH + cg0],   bhz1 = bhh[HH + cg1];
  const float bhn0 = bhh[2*HH + cg0], bhn1 = bhh[2*HH + cg1];

  float hold[2][4];
#pragma unroll
  for (int g = 0; g < 2; ++g)
#pragma unroll
    for (int r = 0; r < 4; ++r) hold[g][r] = 0.f;

  // zero h; stage chunk 0 into buf 0
  for (int e = tid; e < SPB2 * HSTR; e += 1024)
    hs[e / HSTR][e % HSTR] = (_Float16)0.f;
  {
    const _Float16* gs = packW + wid * 2048 + lane * 8;
    _Float16* ls = &wls[0][wid * 2048];
    gload16(gs, ls);
    gload16(gs + 512, ls + 512);
    gload16(gs + 1024, ls + 1024);
    gload16(gs + 1536, ls + 1536);
  }
  __syncthreads();

  for (int t = 0; t < TT; ++t) {
    // ---- issue gi loads early (HBM latency hides under the chunk loop) ----
    float gir[2][4], giz[2][4], gin[2][4];
#pragma unroll
    for (int r = 0; r < 4; ++r) {
      const float* p0 = gi + ((size_t)(seq0 + mrow + r) * TT + t) * G3;
      gir[0][r] = __builtin_nontemporal_load(p0 + cg0);
      giz[0][r] = __builtin_nontemporal_load(p0 + HH + cg0);
      gin[0][r] = __builtin_nontemporal_load(p0 + 2 * HH + cg0);
      gir[1][r] = __builtin_nontemporal_load(p0 + cg1);
      giz[1][r] = __builtin_nontemporal_load(p0 + HH + cg1);
      gin[1][r] = __builtin_nontemporal_load(p0 + 2 * HH + cg1);
    }

    // accumulators: a0=r/g0, a1=r/g1, a2=z/g0, a3=z/g1, a4=n/g0, a5=n/g1
    f32x4 a0 = {0.f,0.f,0.f,0.f}, a1 = {0.f,0.f,0.f,0.f}, a2 = {0.f,0.f,0.f,0.f};
    f32x4 a3 = {0.f,0.f,0.f,0.f}, a4 = {0.f,0.f,0.f,0.f}, a5 = {0.f,0.f,0.f,0.f};

    CH(0,  a0) CH(1,  a0) CH(2,  a0) CH(3,  a0)
    CH(4,  a1) CH(5,  a1) CH(6,  a1) CH(7,  a1)
    CH(8,  a2) CH(9,  a2) CH(10, a2) CH(11, a2)
    CH(12, a3) CH(13, a3) CH(14, a3) CH(15, a3)
    CH(16, a4) CH(17, a4) CH(18, a4) CH(19, a4)
    CH(20, a5) CH(21, a5) CH(22, a5) CH(23, a5)

    // ---- register-local gate epilogue: 2 groups x 4 seqs per lane ----
#pragma unroll
    for (int r = 0; r < 4; ++r) {
      {
        float hr = a0[r] + bhr0;
        float hz = a2[r] + bhz0;
        float hn = a4[r] + bhn0;
        float rr = __builtin_amdgcn_rcpf(1.f + __expf(-(gir[0][r] + hr)));
        float zz = __builtin_amdgcn_rcpf(1.f + __expf(-(giz[0][r] + hz)));
        float ex = __expf(2.f * (gin[0][r] + rr * hn));
        float nn = 1.f - 2.f * __builtin_amdgcn_rcpf(ex + 1.f);
        float hnew = nn + zz * (hold[0][r] - nn);
        hold[0][r] = hnew;
        hs[mrow + r][cg0] = (_Float16)hnew;
        if (yout)
          __builtin_nontemporal_store(hnew, yout + ((size_t)(seq0 + mrow + r) * TT + t) * HH + cg0);
      }
      {
        float hr = a1[r] + bhr1;
        float hz = a3[r] + bhz1;
        float hn = a5[r] + bhn1;
        float rr = __builtin_amdgcn_rcpf(1.f + __expf(-(gir[1][r] + hr)));
        float zz = __builtin_amdgcn_rcpf(1.f + __expf(-(giz[1][r] + hz)));
        float ex = __expf(2.f * (gin[1][r] + rr * hn));
        float nn = 1.f - 2.f * __builtin_amdgcn_rcpf(ex + 1.f);
        float hnew = nn + zz * (hold[1][r] - nn);
        hold[1][r] = hnew;
        hs[mrow + r][cg1] = (_Float16)hnew;
        if (yout)
          __builtin_nontemporal_store(hnew, yout + ((size_t)(seq0 + mrow + r) * TT + t) * HH + cg1);
      }
    }
    __syncthreads();   // h writes visible before next step's chunk computes
  }

#pragma unroll
  for (int r = 0; r < 4; ++r) {
    hfin[(size_t)(seq0 + mrow + r) * HH + cg0] = hold[0][r];
    hfin[(size_t)(seq0 + mrow + r) * HH + cg1] = hold[1][r];
  }
}

// ---------------- fallback fp32 scan (row-streaming) ----------------
#define QS 4
#define SCTH 512
__global__ __launch_bounds__(SCTH) void gru_scan2f(
    const float* __restrict__ gi, const float* __restrict__ W,
    const float* __restrict__ bhh, float* __restrict__ hfin,
    float* __restrict__ yout)
{
  __shared__ __align__(16) float hsl[HH][QS];
  const int col = threadIdx.x;
  const int seq0 = blockIdx.x * QS;
  const float bh0 = bhh[col];
  const float bh1 = bhh[HH + col];
  const float bh2 = bhh[2 * HH + col];
  const float* w0p = W + (size_t)col * HH;
  const float* w1p = W + (size_t)(HH + col) * HH;
  const float* w2p = W + (size_t)(2 * HH + col) * HH;

  *reinterpret_cast<float4*>(&hsl[col][0]) = make_float4(0.f, 0.f, 0.f, 0.f);
  __syncthreads();

  for (int t = 0; t < TT; ++t) {
    float acc0[QS], acc1[QS], acc2[QS];
#pragma unroll
    for (int s = 0; s < QS; ++s) { acc0[s] = bh0; acc1[s] = bh1; acc2[s] = bh2; }
    float4 ho = *reinterpret_cast<const float4*>(&hsl[col][0]);
    float hold[QS] = {ho.x, ho.y, ho.z, ho.w};
#pragma unroll 2
    for (int k0 = 0; k0 < HH; k0 += 4) {
      float w[3][4];
      float4 a = *reinterpret_cast<const float4*>(&w0p[k0]);
      w[0][0] = a.x; w[0][1] = a.y; w[0][2] = a.z; w[0][3] = a.w;
      float4 b = *reinterpret_cast<const float4*>(&w1p[k0]);
      w[1][0] = b.x; w[1][1] = b.y; w[1][2] = b.z; w[1][3] = b.w;
      float4 c = *reinterpret_cast<const float4*>(&w2p[k0]);
      w[2][0] = c.x; w[2][1] = c.y; w[2][2] = c.z; w[2][3] = c.w;
#pragma unroll
      for (int kk = 0; kk < 4; ++kk) {
        float4 h4 = *reinterpret_cast<const float4*>(&hsl[k0 + kk][0]);
        float hq[4] = {h4.x, h4.y, h4.z, h4.w};
#pragma unroll
        for (int s = 0; s < QS; ++s) {
          acc0[s] = fmaf(hq[s], w[0][kk], acc0[s]);
          acc1[s] = fmaf(hq[s], w[1][kk], acc1[s]);
          acc2[s] = fmaf(hq[s], w[2][kk], acc2[s]);
        }
      }
    }
    __syncthreads();
    float hnew[QS];
#pragma unroll
    for (int s = 0; s < QS; ++s) {
      size_t grow = ((size_t)(seq0 + s) * TT + t) * G3;
      float ir = gi[grow + col];
      float iz = gi[grow + HH + col];
      float inn = gi[grow + 2 * HH + col];
      float r = 1.f / (1.f + expf(-(ir + acc0[s])));
      float z = 1.f / (1.f + expf(-(iz + acc1[s])));
      float nn = tanhf(inn + r * acc2[s]);
      hnew[s] = (1.f - z) * nn + z * hold[s];
      if (yout) yout[((size_t)(seq0 + s) * TT + t) * HH + col] = hnew[s];
    }
    *reinterpret_cast<float4*>(&hsl[col][0]) =
        make_float4(hnew[0], hnew[1], hnew[2], hnew[3]);
    __syncthreads();
  }
#pragma unroll
  for (int s = 0; s < QS; ++s)
    hfin[(size_t)(seq0 + s) * HH + col] = hsl[col][s];
}

// ---------------- final FC + channel mean ----------------
__global__ __launch_bounds__(256) void fc_mean(
    const float* __restrict__ hfin, const float* __restrict__ fcW,
    const float* __restrict__ fcb, float* __restrict__ out)
{
  __shared__ float red[256];
  const int b = blockIdx.x;
  const int tid = threadIdx.x;
  float sum = 0.f;
  for (int e = tid; e < CC * HH; e += 256) {
    int c = e >> 9;
    int k = e & (HH - 1);
    sum += hfin[(size_t)(b * CC + c) * HH + k] * fcW[k];
  }
  red[tid] = sum;
  __syncthreads();
  for (int w = 128; w > 0; w >>= 1) {
    if (tid < w) red[tid] += red[tid + w];
    __syncthreads();
  }
  if (tid == 0) out[b] = red[0] * (1.f / CC) + fcb[0];
}

extern "C" void kernel_launch(void* const* d_in, const int* in_sizes, int n_in,
                              void* d_out, int out_size, void* d_ws, size_t ws_size,
                              hipStream_t stream)
{
  const float* x    = (const float*)d_in[0];
  const float* Wih0 = (const float*)d_in[1];
  const float* Whh0 = (const float*)d_in[2];
  const float* bih0 = (const float*)d_in[3];
  const float* bhh0 = (const float*)d_in[4];
  const float* Wih1 = (const float*)d_in[5];
  const float* Whh1 = (const float*)d_in[6];
  const float* bih1 = (const float*)d_in[7];
  const float* bhh1 = (const float*)d_in[8];
  const float* fcW  = (const float*)d_in[9];
  const float* fcb  = (const float*)d_in[10];
  float* out = (float*)d_out;

  // ws layout:
  //   gi   [MROWS][G3] fp32   100,663,296 @ 0
  //   y0   [MROWS][HH] fp32    33,554,432 @ 100,663,296
  //   hfin [NSEQ][HH]  fp32       524,288 @ 134,217,728
  //   pack fp16 1-plane         1,572,864 @ 134,742,016   (end 136,314,880)
  char* ws = (char*)d_ws;
  float* gibuf = (float*)ws;
  float* y0    = (float*)(ws + 100663296ull);
  float* hfin  = (float*)(ws + 134217728ull);
  _Float16* packb = (_Float16*)(ws + 134742016ull);
  const bool mfma_ok = (ws_size >= 136314880ull);

  // layer 0 input GEMM
  gemm_bias<<<dim3(G3 / TNg, MROWS / TMg), 256, 0, stream>>>(x, Wih0, bih0, gibuf, MROWS, G3, FF);

  if (mfma_ok) {
    pack_whh<<<dim3(384), 256, 0, stream>>>(Whh0, packb);
    gru_scan_mfma<<<dim3(NSEQ / SPB2), 1024, 0, stream>>>(gibuf, packb, bhh0, hfin, y0);
  } else {
    gru_scan2f<<<dim3(NSEQ / QS), SCTH, 0, stream>>>(gibuf, Whh0, bhh0, hfin, y0);
  }

  // layer 1 input GEMM (gi reused)
  gemm_bias<<<dim3(G3 / TNg, MROWS / TMg), 256, 0, stream>>>(y0, Wih1, bih1, gibuf, MROWS, G3, HH);

  if (mfma_ok) {
    pack_whh<<<dim3(384), 256, 0, stream>>>(Whh1, packb);
    gru_scan_mfma<<<dim3(NSEQ / SPB2), 1024, 0, stream>>>(gibuf, packb, bhh1, hfin, nullptr);
  } else {
    gru_scan2f<<<dim3(NSEQ / QS), SCTH, 0, stream>>>(gibuf, Whh1, bhh1, hfin, nullptr);
  }

  fc_mean<<<dim3(BB), 256, 0, stream>>>(hfin, fcW, fcb, out);
}

// Round 8
// 2681.066 us; speedup vs baseline: 2.2322x; 2.2322x over previous
//
#include <hip/hip_runtime.h>
#include <math.h>

// Problem dims (fixed by reference)
#define BB 32
#define CC 8
#define TT 64
#define FF 256
#define HH 512
#define G3 1536
#define NSEQ 256            // BB*CC
#define MROWS 16384         // NSEQ*TT

#define SGRP 16             // sequence groups (16 seqs each)
#define NGRP 4              // N-split ways (384 cols each)

typedef _Float16 f16x8 __attribute__((ext_vector_type(8)));
typedef float f32x4 __attribute__((ext_vector_type(4)));

// ---------------- input GEMM: C[M][N] = A[M][K] @ W[N][K]^T + bias[N] ----------------
#define TMg 128
#define TNg 128
#define TKg 16

__global__ __launch_bounds__(256) void gemm_bias(
    const float* __restrict__ A, const float* __restrict__ W,
    const float* __restrict__ bias, float* __restrict__ C,
    int M, int N, int K)
{
  __shared__ float As[TKg][TMg + 4];
  __shared__ float Ws[TKg][TNg + 4];
  const int bm = blockIdx.y * TMg;
  const int bn = blockIdx.x * TNg;
  const int tid = threadIdx.x;
  const int tx = tid & 15;
  const int ty = tid >> 4;
  float acc[8][8];
#pragma unroll
  for (int i = 0; i < 8; ++i)
#pragma unroll
    for (int j = 0; j < 8; ++j) acc[i][j] = 0.f;

  for (int k0 = 0; k0 < K; k0 += TKg) {
    __syncthreads();
#pragma unroll
    for (int i = 0; i < 8; ++i) {
      int e = i * 256 + tid;
      int r = e >> 4;
      int c = e & 15;
      As[c][r] = A[(size_t)(bm + r) * K + (k0 + c)];
      Ws[c][r] = W[(size_t)(bn + r) * K + (k0 + c)];
    }
    __syncthreads();
#pragma unroll
    for (int k = 0; k < TKg; ++k) {
      float a[8], w[8];
#pragma unroll
      for (int i = 0; i < 8; ++i) a[i] = As[k][ty * 8 + i];
#pragma unroll
      for (int j = 0; j < 8; ++j) w[j] = Ws[k][tx + 16 * j];
#pragma unroll
      for (int i = 0; i < 8; ++i)
#pragma unroll
        for (int j = 0; j < 8; ++j) acc[i][j] = fmaf(a[i], w[j], acc[i][j]);
    }
  }
#pragma unroll
  for (int i = 0; i < 8; ++i) {
    size_t m = (size_t)(bm + ty * 8 + i);
#pragma unroll
    for (int j = 0; j < 8; ++j) {
      int n = bn + tx + 16 * j;
      C[m * N + n] = acc[i][j] + bias[n];
    }
  }
}

// ---------------- pack Whh[G3][HH] fp32 -> fp16 B-fragments, N-split order ----------
// P[ng(4)][tl(24)][kc(16)][lane(64)][8]; tl = gate*8 + sub; global tile = gate*32+ng*8+sub
// B-frag (16x16x32_f16): n = lane&15 (Whh row within tile), k = kc*32 + (lane>>4)*8 + i
__global__ __launch_bounds__(256) void pack_whh(
    const float* __restrict__ W, _Float16* __restrict__ P)
{
  int id = blockIdx.x * 256 + threadIdx.x;    // 0 .. 98303
  int lane = id & 63;
  int kc = (id >> 6) & 15;
  int tidx = id >> 10;                        // 0..95 = ng*24 + tl
  int ng = tidx / 24;
  int tl = tidx % 24;
  int g = tl >> 3, sub = tl & 7;
  int gt = g * 32 + ng * 8 + sub;             // global 16-row tile of Whh
  int row = gt * 16 + (lane & 15);
  int k0 = kc * 32 + ((lane >> 4) * 8);
  const float* src = W + (size_t)row * HH + k0;
  f16x8 v;
#pragma unroll
  for (int i = 0; i < 8; ++i) v[i] = (_Float16)src[i];
  *reinterpret_cast<f16x8*>(P + (size_t)id * 8) = v;
}

// ---------------- MFMA recurrent scan, 4-way N-split + flag-sync ----------------
// 64 blocks = 16 seq-groups x 4 N-groups; 512 threads (8 waves, 2/SIMD, VGPR cap 256).
// Block (sg, ng): 16 seqs, preact cols ng*128..+127 for all 3 gates = 24 tiles
// = 384 KB fp16 slice, streamed from L2 each step via 2-deep register pipeline.
// After each step the 4 blocks of a group exchange 128-col h slices via hx (global)
// with a monotonic per-(group,step) flag barrier (device-scope release/acquire).
#define SPB2 16
#define HSTR 520

#define LOADW(buf, g)                                                            \
  {                                                                              \
    const _Float16* _s = packW +                                                 \
        (((size_t)(ng * 24 + (g) * 8 + wid)) * 16) * 512 + (size_t)lane * 8;     \
    _Pragma("unroll")                                                            \
    for (int kc = 0; kc < 16; ++kc)                                              \
      buf[kc] = *reinterpret_cast<const f16x8*>(_s + (size_t)kc * 512);          \
  }

#define MF16(buf, acc)                                                           \
  {                                                                              \
    _Pragma("unroll")                                                            \
    for (int kc = 0; kc < 16; ++kc) {                                            \
      f16x8 _ha = *reinterpret_cast<const f16x8*>(&hs[arow][kc * 32 + agrp * 8]); \
      acc = __builtin_amdgcn_mfma_f32_16x16x32_f16(_ha, buf[kc], acc, 0, 0, 0);  \
    }                                                                            \
  }

__global__ __launch_bounds__(512, 2) void gru_scan_mfma(
    const float* __restrict__ gi,      // [NSEQ][TT][G3]
    const _Float16* __restrict__ packW,
    const float* __restrict__ bhh,     // [G3]
    float* __restrict__ hfin,          // [NSEQ][HH]
    float* __restrict__ yout,          // [NSEQ][TT][HH] or nullptr
    _Float16* __restrict__ hx,         // [2][NSEQ][HH] exchange buffer
    unsigned int* __restrict__ flags)  // [SGRP][TT], zeroed before launch
{
  __shared__ __align__(16) _Float16 hs[SPB2][HSTR];   // 16.6 KB

  const int tid = threadIdx.x;
  const int lane = tid & 63;
  const int wid = tid >> 6;                   // 0..7
  const int bid = blockIdx.x;
  const int sg = bid >> 2;                    // seq group
  const int ng = bid & 3;                     // N group
  const int seq0 = sg * SPB2;

  const int arow = lane & 15;                 // A-frag row (seq)
  const int agrp = lane >> 4;
  const int dcol = lane & 15;                 // D-frag col within tile
  const int mrow = (lane >> 4) * 4;           // D-frag first row (seq)

  const int cg = ng * 128 + wid * 16 + dcol;  // this lane's h column (global)

  const float bhr = bhh[cg];
  const float bhz = bhh[HH + cg];
  const float bhn = bhh[2 * HH + cg];

  float hold[4] = {0.f, 0.f, 0.f, 0.f};

  // zero h state (t=0)
  for (int e = tid; e < SPB2 * HSTR; e += 512)
    hs[e / HSTR][e % HSTR] = (_Float16)0.f;
  __syncthreads();

  for (int t = 0; t < TT; ++t) {
    if (t > 0) {
      // wait for all 4 blocks of this group to publish step t-1
      if (tid == 0) {
        while (__hip_atomic_load(&flags[sg * TT + (t - 1)],
                                 __ATOMIC_ACQUIRE, __HIP_MEMORY_SCOPE_AGENT) < NGRP) {}
      }
      __syncthreads();
      // copy full h state (16 seqs x 512, fp16 = 16 KB) from hx[t&1] into LDS
      {
        const _Float16* src = hx + (size_t)(t & 1) * NSEQ * HH
                              + (size_t)seq0 * HH + (size_t)tid * 16;
        int e0 = tid * 16;
        int row = e0 >> 9;
        int col = e0 & 511;
        *reinterpret_cast<f16x8*>(&hs[row][col])     = *reinterpret_cast<const f16x8*>(src);
        *reinterpret_cast<f16x8*>(&hs[row][col + 8]) = *reinterpret_cast<const f16x8*>(src + 8);
      }
      __syncthreads();
    }

    // ---- gi loads (HBM, nontemporal; consumed in epilogue) ----
    float gir[4], giz[4], gin[4];
#pragma unroll
    for (int r = 0; r < 4; ++r) {
      const float* p0 = gi + ((size_t)(seq0 + mrow + r) * TT + t) * G3;
      gir[r] = __builtin_nontemporal_load(p0 + cg);
      giz[r] = __builtin_nontemporal_load(p0 + HH + cg);
      gin[r] = __builtin_nontemporal_load(p0 + 2 * HH + cg);
    }

    // ---- 3 tiles (r/z/n of this wave's column group), 2-deep register pipeline ----
    f16x8 bufA[16], bufB[16];
    f32x4 aR = {0.f,0.f,0.f,0.f}, aZ = {0.f,0.f,0.f,0.f}, aN = {0.f,0.f,0.f,0.f};
    LOADW(bufA, 0)
    LOADW(bufB, 1)
    MF16(bufA, aR)
    LOADW(bufA, 2)
    MF16(bufB, aZ)
    MF16(bufA, aN)

    // ---- register-local gate epilogue: 4 seqs x 1 col per lane ----
    const int nb = (t + 1) & 1;
#pragma unroll
    for (int r = 0; r < 4; ++r) {
      float hr = aR[r] + bhr;
      float hz = aZ[r] + bhz;
      float hn = aN[r] + bhn;
      float rr = __builtin_amdgcn_rcpf(1.f + __expf(-(gir[r] + hr)));
      float zz = __builtin_amdgcn_rcpf(1.f + __expf(-(giz[r] + hz)));
      float ex = __expf(2.f * (gin[r] + rr * hn));
      float nn = 1.f - 2.f * __builtin_amdgcn_rcpf(ex + 1.f);
      float hnew = nn + zz * (hold[r] - nn);
      hold[r] = hnew;
      hx[(size_t)nb * NSEQ * HH + (size_t)(seq0 + mrow + r) * HH + cg] = (_Float16)hnew;
      if (yout)
        __builtin_nontemporal_store(hnew, yout + ((size_t)(seq0 + mrow + r) * TT + t) * HH + cg);
    }

    // publish step t: all stores device-visible, then one release-add
    __threadfence();
    __syncthreads();
    if (tid == 0)
      __hip_atomic_fetch_add(&flags[sg * TT + t], 1u,
                             __ATOMIC_RELEASE, __HIP_MEMORY_SCOPE_AGENT);
  }

#pragma unroll
  for (int r = 0; r < 4; ++r)
    hfin[(size_t)(seq0 + mrow + r) * HH + cg] = hold[r];
}

// ---------------- fallback fp32 scan (row-streaming) ----------------
#define QS 4
#define SCTH 512
__global__ __launch_bounds__(SCTH) void gru_scan2f(
    const float* __restrict__ gi, const float* __restrict__ W,
    const float* __restrict__ bhh, float* __restrict__ hfin,
    float* __restrict__ yout)
{
  __shared__ __align__(16) float hsl[HH][QS];
  const int col = threadIdx.x;
  const int seq0 = blockIdx.x * QS;
  const float bh0 = bhh[col];
  const float bh1 = bhh[HH + col];
  const float bh2 = bhh[2 * HH + col];
  const float* w0p = W + (size_t)col * HH;
  const float* w1p = W + (size_t)(HH + col) * HH;
  const float* w2p = W + (size_t)(2 * HH + col) * HH;

  *reinterpret_cast<float4*>(&hsl[col][0]) = make_float4(0.f, 0.f, 0.f, 0.f);
  __syncthreads();

  for (int t = 0; t < TT; ++t) {
    float acc0[QS], acc1[QS], acc2[QS];
#pragma unroll
    for (int s = 0; s < QS; ++s) { acc0[s] = bh0; acc1[s] = bh1; acc2[s] = bh2; }
    float4 ho = *reinterpret_cast<const float4*>(&hsl[col][0]);
    float hold[QS] = {ho.x, ho.y, ho.z, ho.w};
#pragma unroll 2
    for (int k0 = 0; k0 < HH; k0 += 4) {
      float w[3][4];
      float4 a = *reinterpret_cast<const float4*>(&w0p[k0]);
      w[0][0] = a.x; w[0][1] = a.y; w[0][2] = a.z; w[0][3] = a.w;
      float4 b = *reinterpret_cast<const float4*>(&w1p[k0]);
      w[1][0] = b.x; w[1][1] = b.y; w[1][2] = b.z; w[1][3] = b.w;
      float4 c = *reinterpret_cast<const float4*>(&w2p[k0]);
      w[2][0] = c.x; w[2][1] = c.y; w[2][2] = c.z; w[2][3] = c.w;
#pragma unroll
      for (int kk = 0; kk < 4; ++kk) {
        float4 h4 = *reinterpret_cast<const float4*>(&hsl[k0 + kk][0]);
        float hq[4] = {h4.x, h4.y, h4.z, h4.w};
#pragma unroll
        for (int s = 0; s < QS; ++s) {
          acc0[s] = fmaf(hq[s], w[0][kk], acc0[s]);
          acc1[s] = fmaf(hq[s], w[1][kk], acc1[s]);
          acc2[s] = fmaf(hq[s], w[2][kk], acc2[s]);
        }
      }
    }
    __syncthreads();
    float hnew[QS];
#pragma unroll
    for (int s = 0; s < QS; ++s) {
      size_t grow = ((size_t)(seq0 + s) * TT + t) * G3;
      float ir = gi[grow + col];
      float iz = gi[grow + HH + col];
      float inn = gi[grow + 2 * HH + col];
      float r = 1.f / (1.f + expf(-(ir + acc0[s])));
      float z = 1.f / (1.f + expf(-(iz + acc1[s])));
      float nn = tanhf(inn + r * acc2[s]);
      hnew[s] = (1.f - z) * nn + z * hold[s];
      if (yout) yout[((size_t)(seq0 + s) * TT + t) * HH + col] = hnew[s];
    }
    *reinterpret_cast<float4*>(&hsl[col][0]) =
        make_float4(hnew[0], hnew[1], hnew[2], hnew[3]);
    __syncthreads();
  }
#pragma unroll
  for (int s = 0; s < QS; ++s)
    hfin[(size_t)(seq0 + s) * HH + col] = hsl[col][s];
}

// ---------------- final FC + channel mean ----------------
__global__ __launch_bounds__(256) void fc_mean(
    const float* __restrict__ hfin, const float* __restrict__ fcW,
    const float* __restrict__ fcb, float* __restrict__ out)
{
  __shared__ float red[256];
  const int b = blockIdx.x;
  const int tid = threadIdx.x;
  float sum = 0.f;
  for (int e = tid; e < CC * HH; e += 256) {
    int c = e >> 9;
    int k = e & (HH - 1);
    sum += hfin[(size_t)(b * CC + c) * HH + k] * fcW[k];
  }
  red[tid] = sum;
  __syncthreads();
  for (int w = 128; w > 0; w >>= 1) {
    if (tid < w) red[tid] += red[tid + w];
    __syncthreads();
  }
  if (tid == 0) out[b] = red[0] * (1.f / CC) + fcb[0];
}

extern "C" void kernel_launch(void* const* d_in, const int* in_sizes, int n_in,
                              void* d_out, int out_size, void* d_ws, size_t ws_size,
                              hipStream_t stream)
{
  const float* x    = (const float*)d_in[0];
  const float* Wih0 = (const float*)d_in[1];
  const float* Whh0 = (const float*)d_in[2];
  const float* bih0 = (const float*)d_in[3];
  const float* bhh0 = (const float*)d_in[4];
  const float* Wih1 = (const float*)d_in[5];
  const float* Whh1 = (const float*)d_in[6];
  const float* bih1 = (const float*)d_in[7];
  const float* bhh1 = (const float*)d_in[8];
  const float* fcW  = (const float*)d_in[9];
  const float* fcb  = (const float*)d_in[10];
  float* out = (float*)d_out;

  // ws layout:
  //   gi   [MROWS][G3] fp32   100,663,296 @ 0
  //   y0   [MROWS][HH] fp32    33,554,432 @ 100,663,296
  //   hfin [NSEQ][HH]  fp32       524,288 @ 134,217,728
  //   pack fp16               1,572,864 @ 134,742,016
  //   hx   [2][NSEQ][HH] fp16   524,288 @ 136,314,880
  //   flags [SGRP][TT] u32        4,096 @ 136,839,168   (end 136,843,264)
  char* ws = (char*)d_ws;
  float* gibuf = (float*)ws;
  float* y0    = (float*)(ws + 100663296ull);
  float* hfin  = (float*)(ws + 134217728ull);
  _Float16* packb = (_Float16*)(ws + 134742016ull);
  _Float16* hx    = (_Float16*)(ws + 136314880ull);
  unsigned int* flags = (unsigned int*)(ws + 136839168ull);
  const bool mfma_ok = (ws_size >= 136843264ull);

  // layer 0 input GEMM
  gemm_bias<<<dim3(G3 / TNg, MROWS / TMg), 256, 0, stream>>>(x, Wih0, bih0, gibuf, MROWS, G3, FF);

  if (mfma_ok) {
    pack_whh<<<dim3(384), 256, 0, stream>>>(Whh0, packb);
    hipMemsetAsync(flags, 0, SGRP * TT * sizeof(unsigned int), stream);
    gru_scan_mfma<<<dim3(SGRP * NGRP), 512, 0, stream>>>(gibuf, packb, bhh0, hfin, y0, hx, flags);
  } else {
    gru_scan2f<<<dim3(NSEQ / QS), SCTH, 0, stream>>>(gibuf, Whh0, bhh0, hfin, y0);
  }

  // layer 1 input GEMM (gi reused)
  gemm_bias<<<dim3(G3 / TNg, MROWS / TMg), 256, 0, stream>>>(y0, Wih1, bih1, gibuf, MROWS, G3, HH);

  if (mfma_ok) {
    pack_whh<<<dim3(384), 256, 0, stream>>>(Whh1, packb);
    hipMemsetAsync(flags, 0, SGRP * TT * sizeof(unsigned int), stream);
    gru_scan_mfma<<<dim3(SGRP * NGRP), 512, 0, stream>>>(gibuf, packb, bhh1, hfin, nullptr, hx, flags);
  } else {
    gru_scan2f<<<dim3(NSEQ / QS), SCTH, 0, stream>>>(gibuf, Whh1, bhh1, hfin, nullptr);
  }

  fc_mean<<<dim3(BB), 256, 0, stream>>>(hfin, fcW, fcb, out);
}

// Round 9
// 2536.660 us; speedup vs baseline: 2.3593x; 1.0569x over previous
//
#include <hip/hip_runtime.h>
#include <math.h>

// Problem dims (fixed by reference)
#define BB 32
#define CC 8
#define TT 64
#define FF 256
#define HH 512
#define G3 1536
#define NSEQ 256            // BB*CC
#define MROWS 16384         // NSEQ*TT

#define SGRP 16             // sequence groups (16 seqs each)
#define NGRP 4              // N-split ways (384 cols each)

typedef _Float16 f16x8 __attribute__((ext_vector_type(8)));
typedef float f32x4 __attribute__((ext_vector_type(4)));

// ---------------- input GEMM: C[M][N] = A[M][K] @ W[N][K]^T + bias[N] ----------------
#define TMg 128
#define TNg 128
#define TKg 16

__global__ __launch_bounds__(256) void gemm_bias(
    const float* __restrict__ A, const float* __restrict__ W,
    const float* __restrict__ bias, float* __restrict__ C,
    int M, int N, int K)
{
  __shared__ float As[TKg][TMg + 4];
  __shared__ float Ws[TKg][TNg + 4];
  const int bm = blockIdx.y * TMg;
  const int bn = blockIdx.x * TNg;
  const int tid = threadIdx.x;
  const int tx = tid & 15;
  const int ty = tid >> 4;
  float acc[8][8];
#pragma unroll
  for (int i = 0; i < 8; ++i)
#pragma unroll
    for (int j = 0; j < 8; ++j) acc[i][j] = 0.f;

  for (int k0 = 0; k0 < K; k0 += TKg) {
    __syncthreads();
#pragma unroll
    for (int i = 0; i < 8; ++i) {
      int e = i * 256 + tid;
      int r = e >> 4;
      int c = e & 15;
      As[c][r] = A[(size_t)(bm + r) * K + (k0 + c)];
      Ws[c][r] = W[(size_t)(bn + r) * K + (k0 + c)];
    }
    __syncthreads();
#pragma unroll
    for (int k = 0; k < TKg; ++k) {
      float a[8], w[8];
#pragma unroll
      for (int i = 0; i < 8; ++i) a[i] = As[k][ty * 8 + i];
#pragma unroll
      for (int j = 0; j < 8; ++j) w[j] = Ws[k][tx + 16 * j];
#pragma unroll
      for (int i = 0; i < 8; ++i)
#pragma unroll
        for (int j = 0; j < 8; ++j) acc[i][j] = fmaf(a[i], w[j], acc[i][j]);
    }
  }
#pragma unroll
  for (int i = 0; i < 8; ++i) {
    size_t m = (size_t)(bm + ty * 8 + i);
#pragma unroll
    for (int j = 0; j < 8; ++j) {
      int n = bn + tx + 16 * j;
      C[m * N + n] = acc[i][j] + bias[n];
    }
  }
}

// ---------------- pack Whh[G3][HH] fp32 -> fp16 B-fragments, N-split order ----------
// P[ng(4)][tl(24)][kc(16)][lane(64)][8]; tl = gate*8 + sub; global tile = gate*32+ng*8+sub
// B-frag (16x16x32_f16): n = lane&15 (Whh row within tile), k = kc*32 + (lane>>4)*8 + i
__global__ __launch_bounds__(256) void pack_whh(
    const float* __restrict__ W, _Float16* __restrict__ P)
{
  int id = blockIdx.x * 256 + threadIdx.x;    // 0 .. 98303
  int lane = id & 63;
  int kc = (id >> 6) & 15;
  int tidx = id >> 10;                        // 0..95 = ng*24 + tl
  int ng = tidx / 24;
  int tl = tidx % 24;
  int g = tl >> 3, sub = tl & 7;
  int gt = g * 32 + ng * 8 + sub;             // global 16-row tile of Whh
  int row = gt * 16 + (lane & 15);
  int k0 = kc * 32 + ((lane >> 4) * 8);
  const float* src = W + (size_t)row * HH + k0;
  f16x8 v;
#pragma unroll
  for (int i = 0; i < 8; ++i) v[i] = (_Float16)src[i];
  *reinterpret_cast<f16x8*>(P + (size_t)id * 8) = v;
}

// ---------------- MFMA recurrent scan, 4-way N-split + flag-sync ----------------
// 64 blocks = 16 seq-groups x 4 N-groups; 512 threads (8 waves, 2/SIMD, VGPR cap 256).
// Block (sg, ng): 16 seqs, preact cols ng*128..+127 for all 3 gates = 24 tiles
// = 384 KB fp16 slice, streamed each step via 2-deep register pipeline.
// After each step the 4 blocks of a group exchange 128-col h slices via hx (global)
// with a monotonic per-(group,step) flag barrier (device-scope release/acquire).
// NOTE: no nontemporal qualifiers — gi/yout must stay L3-resident (round-7 lesson:
// nt gi loads forced 75 MB/scan of HBM traffic at 86 GB/s = the whole scan time).
#define SPB2 16
#define HSTR 520

#define LOADW(buf, g)                                                            \
  {                                                                              \
    const _Float16* _s = packW +                                                 \
        (((size_t)(ng * 24 + (g) * 8 + wid)) * 16) * 512 + (size_t)lane * 8;     \
    _Pragma("unroll")                                                            \
    for (int kc = 0; kc < 16; ++kc)                                              \
      buf[kc] = *reinterpret_cast<const f16x8*>(_s + (size_t)kc * 512);          \
  }

#define MF16(buf, acc)                                                           \
  {                                                                              \
    _Pragma("unroll")                                                            \
    for (int kc = 0; kc < 16; ++kc) {                                            \
      f16x8 _ha = *reinterpret_cast<const f16x8*>(&hs[arow][kc * 32 + agrp * 8]); \
      acc = __builtin_amdgcn_mfma_f32_16x16x32_f16(_ha, buf[kc], acc, 0, 0, 0);  \
    }                                                                            \
  }

__global__ __launch_bounds__(512, 2) void gru_scan_mfma(
    const float* __restrict__ gi,      // [NSEQ][TT][G3]
    const _Float16* __restrict__ packW,
    const float* __restrict__ bhh,     // [G3]
    float* __restrict__ hfin,          // [NSEQ][HH]
    float* __restrict__ yout,          // [NSEQ][TT][HH] or nullptr
    _Float16* __restrict__ hx,         // [2][NSEQ][HH] exchange buffer
    unsigned int* __restrict__ flags)  // [SGRP][TT], zeroed before launch
{
  __shared__ __align__(16) _Float16 hs[SPB2][HSTR];   // 16.6 KB

  const int tid = threadIdx.x;
  const int lane = tid & 63;
  const int wid = tid >> 6;                   // 0..7
  const int bid = blockIdx.x;
  const int sg = bid >> 2;                    // seq group
  const int ng = bid & 3;                     // N group
  const int seq0 = sg * SPB2;

  const int arow = lane & 15;                 // A-frag row (seq)
  const int agrp = lane >> 4;
  const int dcol = lane & 15;                 // D-frag col within tile
  const int mrow = (lane >> 4) * 4;           // D-frag first row (seq)

  const int cg = ng * 128 + wid * 16 + dcol;  // this lane's h column (global)

  const float bhr = bhh[cg];
  const float bhz = bhh[HH + cg];
  const float bhn = bhh[2 * HH + cg];

  float hold[4] = {0.f, 0.f, 0.f, 0.f};

  // zero h state (t=0)
  for (int e = tid; e < SPB2 * HSTR; e += 512)
    hs[e / HSTR][e % HSTR] = (_Float16)0.f;
  __syncthreads();

  for (int t = 0; t < TT; ++t) {
    if (t > 0) {
      // wait for all 4 blocks of this group to publish step t-1
      if (tid == 0) {
        while (__hip_atomic_load(&flags[sg * TT + (t - 1)],
                                 __ATOMIC_ACQUIRE, __HIP_MEMORY_SCOPE_AGENT) < NGRP) {}
      }
      __syncthreads();
      // copy full h state (16 seqs x 512, fp16 = 16 KB) from hx[t&1] into LDS
      {
        const _Float16* src = hx + (size_t)(t & 1) * NSEQ * HH
                              + (size_t)seq0 * HH + (size_t)tid * 16;
        int e0 = tid * 16;
        int row = e0 >> 9;
        int col = e0 & 511;
        *reinterpret_cast<f16x8*>(&hs[row][col])     = *reinterpret_cast<const f16x8*>(src);
        *reinterpret_cast<f16x8*>(&hs[row][col + 8]) = *reinterpret_cast<const f16x8*>(src + 8);
      }
      __syncthreads();
    }

    // ---- gi loads (L3-resident, GEMM-warm; consumed in epilogue) ----
    float gir[4], giz[4], gin[4];
#pragma unroll
    for (int r = 0; r < 4; ++r) {
      const float* p0 = gi + ((size_t)(seq0 + mrow + r) * TT + t) * G3;
      gir[r] = p0[cg];
      giz[r] = p0[HH + cg];
      gin[r] = p0[2 * HH + cg];
    }

    // ---- 3 tiles (r/z/n of this wave's column group), 2-deep register pipeline ----
    f16x8 bufA[16], bufB[16];
    f32x4 aR = {0.f,0.f,0.f,0.f}, aZ = {0.f,0.f,0.f,0.f}, aN = {0.f,0.f,0.f,0.f};
    LOADW(bufA, 0)
    LOADW(bufB, 1)
    MF16(bufA, aR)
    LOADW(bufA, 2)
    MF16(bufB, aZ)
    MF16(bufA, aN)

    // ---- register-local gate epilogue: 4 seqs x 1 col per lane ----
    const int nb = (t + 1) & 1;
#pragma unroll
    for (int r = 0; r < 4; ++r) {
      float hr = aR[r] + bhr;
      float hz = aZ[r] + bhz;
      float hn = aN[r] + bhn;
      float rr = __builtin_amdgcn_rcpf(1.f + __expf(-(gir[r] + hr)));
      float zz = __builtin_amdgcn_rcpf(1.f + __expf(-(giz[r] + hz)));
      float ex = __expf(2.f * (gin[r] + rr * hn));
      float nn = 1.f - 2.f * __builtin_amdgcn_rcpf(ex + 1.f);
      float hnew = nn + zz * (hold[r] - nn);
      hold[r] = hnew;
      hx[(size_t)nb * NSEQ * HH + (size_t)(seq0 + mrow + r) * HH + cg] = (_Float16)hnew;
      if (yout)
        yout[((size_t)(seq0 + mrow + r) * TT + t) * HH + cg] = hnew;
    }

    // publish step t: all stores device-visible, then one release-add
    __threadfence();
    __syncthreads();
    if (tid == 0)
      __hip_atomic_fetch_add(&flags[sg * TT + t], 1u,
                             __ATOMIC_RELEASE, __HIP_MEMORY_SCOPE_AGENT);
  }

#pragma unroll
  for (int r = 0; r < 4; ++r)
    hfin[(size_t)(seq0 + mrow + r) * HH + cg] = hold[r];
}

// ---------------- fallback fp32 scan (row-streaming) ----------------
#define QS 4
#define SCTH 512
__global__ __launch_bounds__(SCTH) void gru_scan2f(
    const float* __restrict__ gi, const float* __restrict__ W,
    const float* __restrict__ bhh, float* __restrict__ hfin,
    float* __restrict__ yout)
{
  __shared__ __align__(16) float hsl[HH][QS];
  const int col = threadIdx.x;
  const int seq0 = blockIdx.x * QS;
  const float bh0 = bhh[col];
  const float bh1 = bhh[HH + col];
  const float bh2 = bhh[2 * HH + col];
  const float* w0p = W + (size_t)col * HH;
  const float* w1p = W + (size_t)(HH + col) * HH;
  const float* w2p = W + (size_t)(2 * HH + col) * HH;

  *reinterpret_cast<float4*>(&hsl[col][0]) = make_float4(0.f, 0.f, 0.f, 0.f);
  __syncthreads();

  for (int t = 0; t < TT; ++t) {
    float acc0[QS], acc1[QS], acc2[QS];
#pragma unroll
    for (int s = 0; s < QS; ++s) { acc0[s] = bh0; acc1[s] = bh1; acc2[s] = bh2; }
    float4 ho = *reinterpret_cast<const float4*>(&hsl[col][0]);
    float hold[QS] = {ho.x, ho.y, ho.z, ho.w};
#pragma unroll 2
    for (int k0 = 0; k0 < HH; k0 += 4) {
      float w[3][4];
      float4 a = *reinterpret_cast<const float4*>(&w0p[k0]);
      w[0][0] = a.x; w[0][1] = a.y; w[0][2] = a.z; w[0][3] = a.w;
      float4 b = *reinterpret_cast<const float4*>(&w1p[k0]);
      w[1][0] = b.x; w[1][1] = b.y; w[1][2] = b.z; w[1][3] = b.w;
      float4 c = *reinterpret_cast<const float4*>(&w2p[k0]);
      w[2][0] = c.x; w[2][1] = c.y; w[2][2] = c.z; w[2][3] = c.w;
#pragma unroll
      for (int kk = 0; kk < 4; ++kk) {
        float4 h4 = *reinterpret_cast<const float4*>(&hsl[k0 + kk][0]);
        float hq[4] = {h4.x, h4.y, h4.z, h4.w};
#pragma unroll
        for (int s = 0; s < QS; ++s) {
          acc0[s] = fmaf(hq[s], w[0][kk], acc0[s]);
          acc1[s] = fmaf(hq[s], w[1][kk], acc1[s]);
          acc2[s] = fmaf(hq[s], w[2][kk], acc2[s]);
        }
      }
    }
    __syncthreads();
    float hnew[QS];
#pragma unroll
    for (int s = 0; s < QS; ++s) {
      size_t grow = ((size_t)(seq0 + s) * TT + t) * G3;
      float ir = gi[grow + col];
      float iz = gi[grow + HH + col];
      float inn = gi[grow + 2 * HH + col];
      float r = 1.f / (1.f + expf(-(ir + acc0[s])));
      float z = 1.f / (1.f + expf(-(iz + acc1[s])));
      float nn = tanhf(inn + r * acc2[s]);
      hnew[s] = (1.f - z) * nn + z * hold[s];
      if (yout) yout[((size_t)(seq0 + s) * TT + t) * HH + col] = hnew[s];
    }
    *reinterpret_cast<float4*>(&hsl[col][0]) =
        make_float4(hnew[0], hnew[1], hnew[2], hnew[3]);
    __syncthreads();
  }
#pragma unroll
  for (int s = 0; s < QS; ++s)
    hfin[(size_t)(seq0 + s) * HH + col] = hsl[col][s];
}

// ---------------- final FC + channel mean ----------------
__global__ __launch_bounds__(256) void fc_mean(
    const float* __restrict__ hfin, const float* __restrict__ fcW,
    const float* __restrict__ fcb, float* __restrict__ out)
{
  __shared__ float red[256];
  const int b = blockIdx.x;
  const int tid = threadIdx.x;
  float sum = 0.f;
  for (int e = tid; e < CC * HH; e += 256) {
    int c = e >> 9;
    int k = e & (HH - 1);
    sum += hfin[(size_t)(b * CC + c) * HH + k] * fcW[k];
  }
  red[tid] = sum;
  __syncthreads();
  for (int w = 128; w > 0; w >>= 1) {
    if (tid < w) red[tid] += red[tid + w];
    __syncthreads();
  }
  if (tid == 0) out[b] = red[0] * (1.f / CC) + fcb[0];
}

extern "C" void kernel_launch(void* const* d_in, const int* in_sizes, int n_in,
                              void* d_out, int out_size, void* d_ws, size_t ws_size,
                              hipStream_t stream)
{
  const float* x    = (const float*)d_in[0];
  const float* Wih0 = (const float*)d_in[1];
  const float* Whh0 = (const float*)d_in[2];
  const float* bih0 = (const float*)d_in[3];
  const float* bhh0 = (const float*)d_in[4];
  const float* Wih1 = (const float*)d_in[5];
  const float* Whh1 = (const float*)d_in[6];
  const float* bih1 = (const float*)d_in[7];
  const float* bhh1 = (const float*)d_in[8];
  const float* fcW  = (const float*)d_in[9];
  const float* fcb  = (const float*)d_in[10];
  float* out = (float*)d_out;

  // ws layout:
  //   gi   [MROWS][G3] fp32   100,663,296 @ 0
  //   y0   [MROWS][HH] fp32    33,554,432 @ 100,663,296
  //   hfin [NSEQ][HH]  fp32       524,288 @ 134,217,728
  //   pack fp16               1,572,864 @ 134,742,016
  //   hx   [2][NSEQ][HH] fp16   524,288 @ 136,314,880
  //   flags [SGRP][TT] u32        4,096 @ 136,839,168   (end 136,843,264)
  char* ws = (char*)d_ws;
  float* gibuf = (float*)ws;
  float* y0    = (float*)(ws + 100663296ull);
  float* hfin  = (float*)(ws + 134217728ull);
  _Float16* packb = (_Float16*)(ws + 134742016ull);
  _Float16* hx    = (_Float16*)(ws + 136314880ull);
  unsigned int* flags = (unsigned int*)(ws + 136839168ull);
  const bool mfma_ok = (ws_size >= 136843264ull);

  // layer 0 input GEMM
  gemm_bias<<<dim3(G3 / TNg, MROWS / TMg), 256, 0, stream>>>(x, Wih0, bih0, gibuf, MROWS, G3, FF);

  if (mfma_ok) {
    pack_whh<<<dim3(384), 256, 0, stream>>>(Whh0, packb);
    hipMemsetAsync(flags, 0, SGRP * TT * sizeof(unsigned int), stream);
    gru_scan_mfma<<<dim3(SGRP * NGRP), 512, 0, stream>>>(gibuf, packb, bhh0, hfin, y0, hx, flags);
  } else {
    gru_scan2f<<<dim3(NSEQ / QS), SCTH, 0, stream>>>(gibuf, Whh0, bhh0, hfin, y0);
  }

  // layer 1 input GEMM (gi reused)
  gemm_bias<<<dim3(G3 / TNg, MROWS / TMg), 256, 0, stream>>>(y0, Wih1, bih1, gibuf, MROWS, G3, HH);

  if (mfma_ok) {
    pack_whh<<<dim3(384), 256, 0, stream>>>(Whh1, packb);
    hipMemsetAsync(flags, 0, SGRP * TT * sizeof(unsigned int), stream);
    gru_scan_mfma<<<dim3(SGRP * NGRP), 512, 0, stream>>>(gibuf, packb, bhh1, hfin, nullptr, hx, flags);
  } else {
    gru_scan2f<<<dim3(NSEQ / QS), SCTH, 0, stream>>>(gibuf, Whh1, bhh1, hfin, nullptr);
  }

  fc_mean<<<dim3(BB), 256, 0, stream>>>(hfin, fcW, fcb, out);
}